// Round 1
// baseline (551.865 us; speedup 1.0000x reference)
//
#include <hip/hip_runtime.h>
#include <hip/hip_bf16.h>
#include <math.h>

#define BB 4
#define TT 200
#define UU 101
#define VV 1024
#define NCELL (BB*TT*UU)   // 80800

__device__ __forceinline__ float f4max(const float4& v) {
    return fmaxf(fmaxf(v.x, v.y), fmaxf(v.z, v.w));
}
__device__ __forceinline__ float f4comp(const float4& v, int c) {
    switch (c & 3) { case 0: return v.x; case 1: return v.y; case 2: return v.z; default: return v.w; }
}

// Kernel 1: one 64-lane wave per (b,t,u) cell. Computes logsumexp over V=1024,
// writes blank_lp[b,t,u] and label_lp[b,t,u] (for u < U-1).
__global__ __launch_bounds__(256) void lse_kernel(
        const float* __restrict__ logits,
        const int*   __restrict__ labels,     // [B, U-1]
        float* __restrict__ blank_lp,         // [B, T, U]
        float* __restrict__ label_lp) {       // [B, T, U-1]
    const int wave = threadIdx.x >> 6;
    const int lane = threadIdx.x & 63;
    const int cell = blockIdx.x * 4 + wave;
    if (cell >= NCELL) return;
    const int b   = cell / (TT * UU);
    const int rem = cell % (TT * UU);
    const int t   = rem / UU;
    const int u   = rem % UU;

    const float4* src = (const float4*)(logits + (size_t)cell * VV);
    float4 x0 = src[lane];
    float4 x1 = src[lane + 64];
    float4 x2 = src[lane + 128];
    float4 x3 = src[lane + 192];

    float m = fmaxf(fmaxf(f4max(x0), f4max(x1)), fmaxf(f4max(x2), f4max(x3)));
    #pragma unroll
    for (int off = 32; off; off >>= 1) m = fmaxf(m, __shfl_xor(m, off));

    float s = 0.f;
    s += __expf(x0.x - m) + __expf(x0.y - m) + __expf(x0.z - m) + __expf(x0.w - m);
    s += __expf(x1.x - m) + __expf(x1.y - m) + __expf(x1.z - m) + __expf(x1.w - m);
    s += __expf(x2.x - m) + __expf(x2.y - m) + __expf(x2.z - m) + __expf(x2.w - m);
    s += __expf(x3.x - m) + __expf(x3.y - m) + __expf(x3.z - m) + __expf(x3.w - m);
    #pragma unroll
    for (int off = 32; off; off >>= 1) s += __shfl_xor(s, off);

    const float lse = m + __logf(s);

    if (lane == 0) blank_lp[cell] = x0.x - lse;   // vocab index 0 lives in lane 0, x0.x

    if (u < UU - 1) {
        int l = labels[b * (UU - 1) + u];
        l = min(max(l, 0), VV - 1);
        const int lane_l = (l >> 2) & 63;
        if (lane == lane_l) {
            const int j = l >> 8;      // which float4 (0..3)
            const int c = l & 3;       // component
            float val = (j == 0) ? f4comp(x0, c) : (j == 1) ? f4comp(x1, c)
                      : (j == 2) ? f4comp(x2, c) : f4comp(x3, c);
            label_lp[(b * TT + t) * (UU - 1) + u] = val - lse;
        }
    }
}

// Kernel 2: anti-diagonal wavefront alpha recursion, one block per batch.
// Thread u owns grid column u. Blank/label values prefetched 4 diagonals ahead.
__global__ __launch_bounds__(128) void alpha_kernel(
        const float* __restrict__ blank_lp,
        const float* __restrict__ label_lp,
        const int*   __restrict__ lab_lens,   // [B]
        const int*   __restrict__ attn,       // [B, T]
        float* __restrict__ loss_b,           // [B]
        int*   __restrict__ valid_b) {        // [B]
    const int b = blockIdx.x;
    const int u = threadIdx.x;

    __shared__ float buf[2][UU];
    __shared__ int   s_part[2];
    __shared__ float s_loss;

    // input length = clip(sum(attn[b,:]), 1, T)
    int acc = 0;
    for (int i = threadIdx.x; i < TT; i += 128) acc += attn[b * TT + i];
    #pragma unroll
    for (int off = 32; off; off >>= 1) acc += __shfl_xor(acc, off);
    if ((threadIdx.x & 63) == 0) s_part[threadIdx.x >> 6] = acc;
    __syncthreads();
    int inlen = s_part[0] + s_part[1];
    inlen = min(max(inlen, 1), TT);
    const int tmax = inlen - 1;
    int lab = lab_lens[b];
    lab = min(max(lab, 0), UU - 1);
    const int ndiag = tmax + lab + 1;

    const float* bl_base = blank_lp + b * TT * UU;
    const float* lb_base = label_lp + b * TT * (UU - 1);
    const int um = min(u, UU - 1);
    const int ul = (um >= 1) ? (um - 1) : 0;

    // fetch blank/label for this thread's cell on diagonal d (clamped, branchless)
    auto fetch = [&](int d, float& fb, float& fl) {
        int tc = d - u;
        tc = min(max(tc, 0), TT - 1);
        fb = bl_base[tc * UU + um];
        fl = lb_base[tc * (UU - 1) + ul];
    };

    float cb[4], cl[4], nb[4], nl[4];
    #pragma unroll
    for (int k = 0; k < 4; ++k) fetch(k, cb[k], cl[k]);

    const int ng = (ndiag + 3) >> 2;
    for (int g = 0; g < ng; ++g) {
        const int dbase = g * 4;
        #pragma unroll
        for (int k = 0; k < 4; ++k) fetch(dbase + 4 + k, nb[k], nl[k]);  // prefetch next group
        #pragma unroll
        for (int k = 0; k < 4; ++k) {
            const int d = dbase + k;
            if (d < ndiag) {
                const int t = d - u;
                const bool act = (u <= lab) && (t >= 0) && (t <= tmax);
                if (act) {
                    const float fb = cb[k], fl = cl[k];
                    float v;
                    if (d == 0) {
                        v = fb;                                   // alpha[0,0]
                    } else if (u == 0) {
                        v = buf[(d - 1) & 1][0] + fb;             // blank-only column
                    } else if (t == 0) {
                        v = buf[(d - 1) & 1][u - 1] + fl;         // label-only row
                    } else {
                        const float a = buf[(d - 1) & 1][u] + fb;
                        const float c = buf[(d - 1) & 1][u - 1] + fl;
                        const float mx = fmaxf(a, c), mn = fminf(a, c);
                        v = mx + log1pf(__expf(mn - mx));
                    }
                    buf[d & 1][u] = v;
                    if (t == tmax && u == lab) s_loss = -v;
                }
            }
            __syncthreads();
        }
        #pragma unroll
        for (int k = 0; k < 4; ++k) { cb[k] = nb[k]; cl[k] = nl[k]; }
    }

    if (threadIdx.x == 0) {
        loss_b[b]  = s_loss;
        valid_b[b] = (lab > 0) ? 1 : 0;    // inlen >= 1 always after clip
    }
}

// Kernel 3: mean over valid batch elements.
__global__ void finalize_kernel(const float* __restrict__ loss_b,
                                const int* __restrict__ valid_b,
                                float* __restrict__ out) {
    if (threadIdx.x == 0 && blockIdx.x == 0) {
        float s = 0.f;
        int nv = 0;
        for (int b = 0; b < BB; ++b) {
            if (valid_b[b]) { s += loss_b[b]; ++nv; }
        }
        out[0] = s / (float)max(nv, 1);
    }
}

extern "C" void kernel_launch(void* const* d_in, const int* in_sizes, int n_in,
                              void* d_out, int out_size, void* d_ws, size_t ws_size,
                              hipStream_t stream) {
    const float* logits   = (const float*)d_in[0];
    const int*   labels   = (const int*)d_in[1];
    const int*   lab_lens = (const int*)d_in[2];
    const int*   attn     = (const int*)d_in[3];

    float* ws      = (float*)d_ws;
    float* blank   = ws;                           // B*T*U
    float* label   = blank + BB * TT * UU;         // B*T*(U-1)
    float* loss_b  = label + BB * TT * (UU - 1);   // B
    int*   valid_b = (int*)(loss_b + BB);          // B

    lse_kernel<<<(NCELL + 3) / 4, 256, 0, stream>>>(logits, labels, blank, label);
    alpha_kernel<<<BB, 128, 0, stream>>>(blank, label, lab_lens, attn, loss_b, valid_b);
    finalize_kernel<<<1, 64, 0, stream>>>(loss_b, valid_b, (float*)d_out);
}